// Round 6
// baseline (1643.419 us; speedup 1.0000x reference)
//
#include <hip/hip_runtime.h>
#include <hip/hip_bf16.h>
#include <cstdint>

#define DEV __device__ __forceinline__

typedef __hip_bfloat16 bf16;
typedef unsigned short u16;
typedef unsigned int u32;
typedef __attribute__((ext_vector_type(8))) short s8v;   // 8 bf16 (4 VGPRs) MFMA A/B frag
typedef __attribute__((ext_vector_type(4))) float f4;    // MFMA C/D frag

static constexpr int Bn = 128;
static constexpr int Tn = 256;
static constexpr int Dn = 384;
static constexpr int Hn = 6;
static constexpr int HDn = 64;
static constexpr int FFn = 1536;
static constexpr int Vn = 95;
static constexpr int Mn = Bn * 256;   // 32768

DEV u16 f2b(float f) {
  bf16 h = __float2bfloat16(f);
  return *reinterpret_cast<u16*>(&h);
}
DEV u32 pk2(float a, float b) { return (u32)f2b(a) | ((u32)f2b(b) << 16); }

// async 16B global->LDS. LDS destination is wave-uniform base + lane*16.
DEV void gl_lds16(const void* g, void* l) {
  auto gp = (const __attribute__((address_space(1))) u32*)(uintptr_t)g;
  auto lp = (__attribute__((address_space(3))) u32*)(u32)(uintptr_t)l;
  __builtin_amdgcn_global_load_lds(gp, lp, 16, 0, 0);
}

// ---------------------------------------------------------------------------
// GEMM — R6: BOTH operands staged through double-buffered LDS.
//
// R0-R5 invariant: MfmaUtil pinned 20-25% across five schedule variants, all
// of which loaded B from global per-wave in the inner loop. B-bytes/MFMA from
// L2 was constant (~256B) across every variant: demand ~79 B/cy/CU (B 53 +
// A-stage 26) vs ~56 B/cy/CU per-CU L2 share -> the K-loop was L2-BW-capped
// on the B path. Fix: stage B via global_load_lds too (B is stored in
// wave-linear fragment order -> linear LDS dest, conflict-free frag reads).
// Inner loop is now pure LDS+MFMA; 2x less B L2 traffic (wy-dup gone).
//
// Schedule (T3 minimum 2-phase): per K-iter:
//   vmcnt(0)  [stage(i) complete]
//   s_barrier [all waves done reading buf(i-1) -> WAR-safe to overwrite]
//   issue STAGE A,B (i+1) -> buf(i^1)
//   ds_read A,B frags from buf(i) + 32/48 MFMA
// MODE 0: bf16 out [M,N]   MODE 3: f32 head out [M,95] col-guarded
// MODE 4: fused QKV: n<384 q; n<768 k; n>=768 v in vT layout [(b,h)][d][t]
// 128x128 tile, BK=64, 4 waves (2x2), wave 64x64. LDS 64KB -> 2 blocks/CU.
// ---------------------------------------------------------------------------
template <int MODE, bool RELU, int NKT, int NT>
__global__ __launch_bounds__(256, 2) void gemm_h(
    const u16* __restrict__ A, const u16* __restrict__ Bw,
    const float* __restrict__ bias, const float* __restrict__ resid,
    void* __restrict__ outp)
{
  constexpr int K = NKT * 64;
  constexpr int N = NT * 16;
  constexpr int nTiles = NT / 8;
  __shared__ __align__(16) u16 As[2][128 * 64];
  __shared__ __align__(16) u16 Bs[2][8192];       // 2 ks x 8 nt x 512
  const int tid = threadIdx.x;
  const int lane = tid & 63, wave = tid >> 6;
  const int quad = lane >> 4, l16 = lane & 15;
  const int wy = wave >> 1, wx = wave & 1;
  const int blk = blockIdx.x;
  const int xcd = blk & 7, tt = blk >> 3;
  const int nT = tt % nTiles, mT = xcd + 8 * (tt / nTiles);
  const int mBase = mT * 128, nBase = nT * 128;

  f4 acc[4][4] = {};

  int rS[4], cS[4];
#pragma unroll
  for (int i = 0; i < 4; i++) {
    int s = i * 256 + tid;
    rS[i] = s >> 3;
    cS[i] = ((s & 7) ^ (rS[i] & 7)) * 8;
  }

  const u16* Ab = A + (size_t)mBase * K;
  const u16* Bp0 = Bw + (size_t)(nBase >> 4) * 512;   // base nt-chunk

#define STAGEA(buf, kt)                                                       \
  do {                                                                        \
    _Pragma("unroll")                                                         \
    for (int i = 0; i < 4; i++)                                               \
      gl_lds16(Ab + (size_t)rS[i] * K + (kt) + cS[i],                         \
               &As[buf][(i * 256 + wave * 64) * 8]);                          \
  } while (0)

#define STAGEB(buf, ikk)                                                      \
  do {                                                                        \
    _Pragma("unroll")                                                         \
    for (int L = 0; L < 4; L++) {                                             \
      int ks = L >> 1, hf = L & 1;                                            \
      gl_lds16(Bp0 + (size_t)((ikk) * 2 + ks) * (NT * 512) + hf * 2048 + tid * 8, \
               &Bs[buf][ks * 4096 + hf * 2048 + tid * 8]);                    \
    }                                                                         \
  } while (0)

  STAGEA(0, 0);
  STAGEB(0, 0);

  const int nk = NKT;
#pragma unroll
  for (int ik = 0; ik < nk; ik++) {
    const int cur = ik & 1;
    asm volatile("s_waitcnt vmcnt(0)" ::: "memory");   // stage(ik) complete
    asm volatile("s_barrier" ::: "memory");            // WAR: buf(ik^1) free
    if (ik + 1 < nk) {
      STAGEA(cur ^ 1, (ik + 1) * 64);
      STAGEB(cur ^ 1, ik + 1);
    }
    __builtin_amdgcn_sched_barrier(0);
#pragma unroll
    for (int ks = 0; ks < 2; ks++) {
      s8v af[4], bq[4];
#pragma unroll
      for (int i = 0; i < 4; i++) {
        int row = wy * 64 + i * 16 + l16;
        int ch = (ks * 4 + quad) ^ (row & 7);
        af[i] = *(const s8v*)&As[cur][row * 64 + ch * 8];
      }
#pragma unroll
      for (int j = 0; j < 4; j++)
        bq[j] = *(const s8v*)&Bs[cur][ks * 4096 + (wx * 4 + j) * 512 + lane * 8];
#pragma unroll
      for (int i = 0; i < 4; i++)
#pragma unroll
        for (int j = 0; j < 4; j++)
          acc[i][j] = __builtin_amdgcn_mfma_f32_16x16x32_bf16(af[i], bq[j], acc[i][j], 0, 0, 0);
    }
  }
#undef STAGEA
#undef STAGEB

  // epilogue: C(i,j,r): m = mBase+wy*64+i*16+quad*4+r, n = nBase+wx*64+j*16+l16
  if (MODE == 0) {
    u16* out = (u16*)outp;
#pragma unroll
    for (int j = 0; j < 4; j++) {
      int n = nBase + wx * 64 + j * 16 + l16;
      float bv = bias ? bias[n] : 0.f;
#pragma unroll
      for (int i = 0; i < 4; i++) {
        int m0 = mBase + wy * 64 + i * 16 + quad * 4;
#pragma unroll
        for (int r = 0; r < 4; r++) {
          float v = acc[i][j][r] + bv;
          if (RELU) v = fmaxf(v, 0.f);
          out[(size_t)(m0 + r) * N + n] = f2b(v);
        }
      }
    }
  } else if (MODE == 3) {
    float* out = (float*)outp;
#pragma unroll
    for (int j = 0; j < 4; j++) {
      int n = nBase + wx * 64 + j * 16 + l16;
      if (n < Vn) {
        float bv = bias[n];
#pragma unroll
        for (int i = 0; i < 4; i++) {
          int m0 = mBase + wy * 64 + i * 16 + quad * 4;
#pragma unroll
          for (int r = 0; r < 4; r++)
            out[(size_t)(m0 + r) * Vn + n] = acc[i][j][r] + bv;
        }
      }
    }
  } else if (MODE == 4) {
    u16* qb = (u16*)outp;
    u16* kb = qb + (size_t)Mn * 384;
    u16* vb = kb + (size_t)Mn * 384;
#pragma unroll
    for (int j = 0; j < 4; j++) {
      int n = nBase + wx * 64 + j * 16 + l16;
      if (n < 768) {
        u16* dst = (n < 384) ? qb : kb;
        int col = (n < 384) ? n : (n - 384);   // 384 is NOT pow2 — no mask!
#pragma unroll
        for (int i = 0; i < 4; i++) {
          int m0 = mBase + wy * 64 + i * 16 + quad * 4;
#pragma unroll
          for (int r = 0; r < 4; r++)
            dst[(size_t)(m0 + r) * 384 + col] = f2b(acc[i][j][r]);
        }
      } else {
        int n7 = n - 768;
        int hh = n7 >> 6, d = n7 & 63;
#pragma unroll
        for (int i = 0; i < 4; i++) {
          int m0 = mBase + wy * 64 + i * 16 + quad * 4;
          int b = m0 >> 8, t0 = m0 & 255;
          uint2 w;
          w.x = pk2(acc[i][j][0], acc[i][j][1]);
          w.y = pk2(acc[i][j][2], acc[i][j][3]);
          *(uint2*)&vb[((b * Hn + hh) * HDn + d) * Tn + t0] = w;
        }
      }
    }
  }
}

// ---------------------------------------------------------------------------
// GEMM + residual-add + LayerNorm fusion (N=384 full-row tile) — R6: B in LDS.
// 128 x 384 tile, 8 waves (512 thr), wave 64 x 96 (wy=wave>>2, wx=wave&3).
//   x[m][n] = resid[m][n] + C[m][n] + bias[n]                (f32, written)
//   h[m][n] = (x-mean_row)*rsqrt(var_row+eps)*sc[n]+bi[n]    (bf16, written)
// LDS: A dbuf 32KB + B dbuf 96KB (2ks x 24nt x 512) + red 4KB = 132KB,
// 1 block/CU. Same single-barrier depth-1 schedule as gemm_h.
// ---------------------------------------------------------------------------
template <int NKT>
__global__ __launch_bounds__(512, 2) void gemm_ln(
    const u16* __restrict__ A, const u16* __restrict__ Bw,
    const float* __restrict__ bias, const float* __restrict__ resid,
    float* __restrict__ xout,
    const float* __restrict__ sc, const float* __restrict__ bi,
    u16* __restrict__ hout)
{
  constexpr int K = NKT * 64;
  constexpr int NT = 24;               // 384 / 16
  __shared__ __align__(16) u16 As[2][128 * 64];
  __shared__ __align__(16) u16 Bs[2][24576];      // 2 ks x 24 nt x 512
  __shared__ float2 red[4][128];
  const int tid = threadIdx.x;
  const int lane = tid & 63, wave = tid >> 6;       // 0..7
  const int quad = lane >> 4, l16 = lane & 15;
  const int wy = wave >> 2, wx = wave & 3;          // 2 x 4
  const int blk = blockIdx.x;
  const int mT = (blk & 7) + 8 * (blk >> 3);        // XCD-major
  const int mBase = mT * 128;

  f4 acc[4][6] = {};

  int rS[2], cS[2];
#pragma unroll
  for (int i = 0; i < 2; i++) {
    int s = i * 512 + tid;
    rS[i] = s >> 3;
    cS[i] = ((s & 7) ^ (rS[i] & 7)) * 8;
  }

  const u16* Ab = A + (size_t)mBase * K;

#define STAGEL(buf, kt)                                                       \
  do {                                                                        \
    _Pragma("unroll")                                                         \
    for (int i = 0; i < 2; i++)                                               \
      gl_lds16(Ab + (size_t)rS[i] * K + (kt) + cS[i],                         \
               &As[buf][(i * 512 + wave * 64) * 8]);                          \
  } while (0)

#define STAGEBL(buf, ikk)                                                     \
  do {                                                                        \
    _Pragma("unroll")                                                         \
    for (int L = 0; L < 6; L++) {                                             \
      int ks = L >> 1, th = L & 1;  /* placeholder, fixed below */            \
      (void)ks; (void)th;                                                     \
    }                                                                         \
  } while (0)

  // B stage: per ks region = 24 nt x 512 = 12288 u16 = 3 rounds of 512thr*8
#define STAGEB2(buf, ikk)                                                     \
  do {                                                                        \
    _Pragma("unroll")                                                         \
    for (int L = 0; L < 6; L++) {                                             \
      int ks = L / 3, th = L % 3;                                             \
      int c = th * 4096 + tid * 8;                                            \
      gl_lds16(Bw + (size_t)((ikk) * 2 + ks) * (NT * 512) + c,                \
               &Bs[buf][ks * 12288 + c]);                                     \
    }                                                                         \
  } while (0)

  STAGEL(0, 0);
  STAGEB2(0, 0);

  const int nk = NKT;
#pragma unroll
  for (int ik = 0; ik < nk; ik++) {
    const int cur = ik & 1;
    asm volatile("s_waitcnt vmcnt(0)" ::: "memory");
    asm volatile("s_barrier" ::: "memory");
    if (ik + 1 < nk) {
      STAGEL(cur ^ 1, (ik + 1) * 64);
      STAGEB2(cur ^ 1, ik + 1);
    }
    __builtin_amdgcn_sched_barrier(0);
#pragma unroll
    for (int ks = 0; ks < 2; ks++) {
      s8v af[4], bq[6];
#pragma unroll
      for (int i = 0; i < 4; i++) {
        int row = wy * 64 + i * 16 + l16;
        int ch = (ks * 4 + quad) ^ (row & 7);
        af[i] = *(const s8v*)&As[cur][row * 64 + ch * 8];
      }
#pragma unroll
      for (int j = 0; j < 6; j++)
        bq[j] = *(const s8v*)&Bs[cur][ks * 12288 + (wx * 6 + j) * 512 + lane * 8];
#pragma unroll
      for (int i = 0; i < 4; i++)
#pragma unroll
        for (int j = 0; j < 6; j++)
          acc[i][j] = __builtin_amdgcn_mfma_f32_16x16x32_bf16(af[i], bq[j], acc[i][j], 0, 0, 0);
    }
  }
#undef STAGEL
#undef STAGEB2

  // ---- epilogue: x = resid + C + bias; row stats; h = LN(x)*sc + bi ----
  f4 psum[4] = {}, psq[4] = {};   // [i], component = r
#pragma unroll
  for (int j = 0; j < 6; j++) {
    int n = wx * 96 + j * 16 + l16;
    float bv = bias[n];
#pragma unroll
    for (int i = 0; i < 4; i++) {
      int m0 = mBase + wy * 64 + i * 16 + quad * 4;
#pragma unroll
      for (int r = 0; r < 4; r++) {
        int m = m0 + r;
        float v = resid[(size_t)m * Dn + n] + acc[i][j][r] + bv;
        xout[(size_t)m * Dn + n] = v;
        acc[i][j][r] = v;
        psum[i][r] += v;
        psq[i][r] += v * v;
      }
    }
  }
  // reduce across the 16-lane l16 group (row invariant in l16)
#pragma unroll
  for (int o = 1; o < 16; o <<= 1)
#pragma unroll
    for (int i = 0; i < 4; i++)
#pragma unroll
      for (int r = 0; r < 4; r++) {
        psum[i][r] += __shfl_xor(psum[i][r], o);
        psq[i][r] += __shfl_xor(psq[i][r], o);
      }
  if (l16 == 0) {
#pragma unroll
    for (int i = 0; i < 4; i++)
#pragma unroll
      for (int r = 0; r < 4; r++) {
        int lr = wy * 64 + i * 16 + quad * 4 + r;
        float2 p; p.x = psum[i][r]; p.y = psq[i][r];
        red[wx][lr] = p;
      }
  }
  __syncthreads();
  float scv[6], biv[6];
#pragma unroll
  for (int j = 0; j < 6; j++) {
    int n = wx * 96 + j * 16 + l16;
    scv[j] = sc[n];
    biv[j] = bi[n];
  }
#pragma unroll
  for (int i = 0; i < 4; i++)
#pragma unroll
    for (int r = 0; r < 4; r++) {
      int lr = wy * 64 + i * 16 + quad * 4 + r;
      float ts = 0.f, tq = 0.f;
#pragma unroll
      for (int w = 0; w < 4; w++) { float2 p = red[w][lr]; ts += p.x; tq += p.y; }
      float mean = ts * (1.f / 384.f);
      float inv = rsqrtf(tq * (1.f / 384.f) - mean * mean + 1e-5f);
      int m = mBase + lr;
#pragma unroll
      for (int j = 0; j < 6; j++) {
        int n = wx * 96 + j * 16 + l16;
        hout[(size_t)m * Dn + n] = f2b((acc[i][j][r] - mean) * inv * scv[j] + biv[j]);
      }
    }
}

// ---------------------------------------------------------------------------
// Flash-chunked attention v2 (unchanged).
// ---------------------------------------------------------------------------
__global__ __launch_bounds__(256) void attn_kernel(
    const u16* __restrict__ q, const u16* __restrict__ k,
    const u16* __restrict__ vT, u16* __restrict__ ao)
{
  __shared__ __align__(16) u16 Ps[4][2][16 * 40];
  const int tid = threadIdx.x, lane = tid & 63, wave = tid >> 6;
  const int quad = lane >> 4, l16 = lane & 15;
  const int c4 = blockIdx.x / 768;
  const int bh = blockIdx.x - c4 * 768;
  const int b = bh / Hn, h = bh % Hn;
  const u16* qg = q + (b * Tn) * Dn + h * HDn;
  const u16* kg = k + (b * Tn) * Dn + h * HDn;
  const u16* vg = vT + bh * (HDn * Tn);
  u16* aog = ao + (b * Tn) * Dn + h * HDn;
  const float c1 = 0.125f * 1.44269504f;  // scale * log2(e)

  const int qt = (wave & 2) ? ((wave & 1) ? 15 - c4 : 8 + c4)
                            : ((wave & 1) ? 7 - c4 : c4);
  const int qglob = qt * 16 + l16;

  const s8v qf0 = *(const s8v*)&qg[qglob * Dn + quad * 8];
  const s8v qf1 = *(const s8v*)&qg[qglob * Dn + 32 + quad * 8];

  float lsum = 0.f;
  f4 O[4] = {};

  const int nch = qt / 2 + 1;
  for (int c2 = 0; c2 < nch; c2++) {
    const int kk0 = c2 * 32;
    f4 S0 = {0.f, 0.f, 0.f, 0.f}, S1 = S0;
    {
      s8v kf = *(const s8v*)&kg[(kk0 + l16) * Dn + quad * 8];
      S0 = __builtin_amdgcn_mfma_f32_16x16x32_bf16(kf, qf0, S0, 0, 0, 0);
      kf = *(const s8v*)&kg[(kk0 + l16) * Dn + 32 + quad * 8];
      S0 = __builtin_amdgcn_mfma_f32_16x16x32_bf16(kf, qf1, S0, 0, 0, 0);
    }
    if (kk0 + 16 <= qt * 16) {  // second 16-row K tile inside causal bound
      s8v kf = *(const s8v*)&kg[(kk0 + 16 + l16) * Dn + quad * 8];
      S1 = __builtin_amdgcn_mfma_f32_16x16x32_bf16(kf, qf0, S1, 0, 0, 0);
      kf = *(const s8v*)&kg[(kk0 + 16 + l16) * Dn + 32 + quad * 8];
      S1 = __builtin_amdgcn_mfma_f32_16x16x32_bf16(kf, qf1, S1, 0, 0, 0);
    }
    const int kkq = kk0 + quad * 4;
    f4 E0, E1;
#pragma unroll
    for (int r = 0; r < 4; r++) {
      E0[r] = (kkq + r <= qglob) ? exp2f(S0[r] * c1) : 0.f;
      E1[r] = (kkq + 16 + r <= qglob) ? exp2f(S1[r] * c1) : 0.f;
      lsum += E0[r] + E1[r];
    }
    u16* prow = &Ps[wave][c2 & 1][l16 * 40];
    uint2 w0, w1;
    w0.x = pk2(E0[0], E0[1]); w0.y = pk2(E0[2], E0[3]);
    w1.x = pk2(E1[0], E1[1]); w1.y = pk2(E1[2], E1[3]);
    *(uint2*)&prow[quad * 4] = w0;
    *(uint2*)&prow[16 + quad * 4] = w1;
    const s8v pf = *(const s8v*)&prow[quad * 8];
#pragma unroll
    for (int dm = 0; dm < 4; dm++) {
      s8v vf = *(const s8v*)&vg[(dm * 16 + l16) * Tn + kk0 + quad * 8];
      O[dm] = __builtin_amdgcn_mfma_f32_16x16x32_bf16(vf, pf, O[dm], 0, 0, 0);
    }
  }

  lsum += __shfl_xor(lsum, 16);
  lsum += __shfl_xor(lsum, 32);
  const float inv = 1.0f / lsum;
#pragma unroll
  for (int dm = 0; dm < 4; dm++) {
    uint2 w;
    w.x = pk2(O[dm][0] * inv, O[dm][1] * inv);
    w.y = pk2(O[dm][2] * inv, O[dm][3] * inv);
    *(uint2*)&aog[qglob * Dn + dm * 16 + quad * 4] = w;
  }
}

// ---------------------------------------------------------------------------
// LayerNorm: one wave per token — used ONCE (after embed, layer-0 LN1).
// ---------------------------------------------------------------------------
__global__ __launch_bounds__(256) void ln_kernel(
    const float* __restrict__ x, const float* __restrict__ sc,
    const float* __restrict__ bi, u16* __restrict__ out)
{
  int tok = blockIdx.x * 4 + (threadIdx.x >> 6);
  int lane = threadIdx.x & 63;
  const float* xr = x + (size_t)tok * Dn;
  float v[6];
  float s = 0.f, sq = 0.f;
#pragma unroll
  for (int i = 0; i < 6; i++) {
    v[i] = xr[lane + 64 * i];
    s += v[i];
    sq += v[i] * v[i];
  }
#pragma unroll
  for (int o = 1; o < 64; o <<= 1) {
    s += __shfl_xor(s, o);
    sq += __shfl_xor(sq, o);
  }
  float mean = s * (1.f / 384.f);
  float var = sq * (1.f / 384.f) - mean * mean;
  float inv = rsqrtf(var + 1e-5f);
  u16* orow = out + (size_t)tok * Dn;
#pragma unroll
  for (int i = 0; i < 6; i++) {
    int c = lane + 64 * i;
    orow[c] = f2b((v[i] - mean) * inv * sc[c] + bi[c]);
  }
}

// x[m][:] = tok_emb[idx[m]][:] + pos_emb[m%T][:]  (float4 per thread)
__global__ __launch_bounds__(256) void embed_kernel(
    const int* __restrict__ idx, const float* __restrict__ tok,
    const float* __restrict__ pos, float* __restrict__ x)
{
  int i = blockIdx.x * 256 + threadIdx.x;  // [0, M*96)
  int m = i / 96, c = (i - m * 96) * 4;
  int t = m & (Tn - 1);
  const float4 tv = *(const float4*)&tok[idx[m] * Dn + c];
  const float4 pv = *(const float4*)&pos[t * Dn + c];
  float4 r;
  r.x = tv.x + pv.x; r.y = tv.y + pv.y; r.z = tv.z + pv.z; r.w = tv.w + pv.w;
  *(float4*)&x[m * Dn + c] = r;
}

// ---------------------------------------------------------------------------
// Weight converter -> MFMA B-fragment order (R7-verified).
// dst[((l*KC + kc)*NTtot + ntoff + nt)*512 + lane*8 + j8] = w[l][k][n] (bf16)
//   where k = kc*32 + (lane>>4)*8 + j8, n = nt*16 + (lane&15), zero if n >= C.
// ---------------------------------------------------------------------------
__global__ __launch_bounds__(256) void tcvt_frag(
    const float* __restrict__ src, u16* __restrict__ dst,
    int K, int C, int NTsub, int NTtot, int ntoff, int total)
{
  int t = blockIdx.x * 256 + threadIdx.x;
  if (t >= total) return;
  int j8 = t & 7;
  int lane = (t >> 3) & 63;
  int rest = t >> 9;
  int nt = rest % NTsub;
  int lkc = rest / NTsub;
  int KC = K >> 5;
  int kc = lkc % KC;
  int l = lkc / KC;
  int quad = lane >> 4, l16 = lane & 15;
  int k = kc * 32 + quad * 8 + j8;
  int n = nt * 16 + l16;
  float v = (n < C) ? src[((size_t)l * K + k) * C + n] : 0.f;
  dst[((size_t)(l * KC + kc) * NTtot + ntoff + nt) * 512 + lane * 8 + j8] = f2b(v);
}

extern "C" void kernel_launch(void* const* d_in, const int* in_sizes, int n_in,
                              void* d_out, int out_size, void* d_ws, size_t ws_size,
                              hipStream_t stream)
{
  (void)in_sizes; (void)n_in; (void)out_size;
  const int*   idx     = (const int*)d_in[0];
  const float* tok_emb = (const float*)d_in[1];
  const float* pos_emb = (const float*)d_in[2];
  const float* ln1_s   = (const float*)d_in[3];
  const float* ln1_b   = (const float*)d_in[4];
  const float* wq      = (const float*)d_in[5];
  const float* wk      = (const float*)d_in[6];
  const float* wv      = (const float*)d_in[7];
  const float* wo      = (const float*)d_in[8];
  const float* bo      = (const float*)d_in[9];
  const float* ln2_s   = (const float*)d_in[10];
  const float* ln2_b   = (const float*)d_in[11];
  const float* w1      = (const float*)d_in[12];
  const float* b1      = (const float*)d_in[13];
  const float* w2      = (const float*)d_in[14];
  const float* b2      = (const float*)d_in[15];
  const float* lnf_s   = (const float*)d_in[16];
  const float* lnf_b   = (const float*)d_in[17];
  const float* head_w  = (const float*)d_in[18];
  const float* head_b  = (const float*)d_in[19];
  float* out = (float*)d_out;

  // workspace layout (bytes)
  char* ws = (char*)d_ws;
  float* x  = (float*)(ws + 0);             // 50,331,648  fp32 residual stream
  u16*   h  = (u16*)(ws + 50331648);        // 25,165,824  LN output (bf16)
  u16*   qb = (u16*)(ws + 75497472);        // 25,165,824  (q,k,v contiguous!)
  u16*   kb = (u16*)(ws + 100663296);       // 25,165,824
  u16*   vb = (u16*)(ws + 125829120);       // 25,165,824  V^T [(b,h)][d][t]
  u16*   ab = (u16*)(ws + 150994944);       // 25,165,824  attn out
  u16*   f1 = qb;                           // alias (q..ab region) for FFN1 out
  u16* qkvT = (u16*)(ws + 176160768);       // 6 * 442368 (frag layout, NTtot=72)
  u16* woT  = qkvT + 6 * 442368;            // 6 * 147456 (NTtot=24)
  u16* w1T  = woT + 6 * 147456;             // 6 * 589824 (NTtot=96, K=384)
  u16* w2T  = w1T + 6 * 589824;             // 6 * 589824 (NTtot=24, K=1536)
  u16* hdT  = w2T + 6 * 589824;             // 49152 (NTtot=8, 95->128 pad)
  if (ws_size < (size_t)197492736) return;

  int tot = 6 * 384 * 384;
  tcvt_frag<<<(tot + 255) / 256, 256, 0, stream>>>(wq, qkvT, 384, 384, 24, 72, 0, tot);
  tcvt_frag<<<(tot + 255) / 256, 256, 0, stream>>>(wk, qkvT, 384, 384, 24, 72, 24, tot);
  tcvt_frag<<<(tot + 255) / 256, 256, 0, stream>>>(wv, qkvT, 384, 384, 24, 72, 48, tot);
  tcvt_frag<<<(tot + 255) / 256, 256, 0, stream>>>(wo, woT, 384, 384, 24, 24, 0, tot);
  tot = 6 * 384 * 1536;
  tcvt_frag<<<(tot + 255) / 256, 256, 0, stream>>>(w1, w1T, 384, 1536, 96, 96, 0, tot);
  tcvt_frag<<<(tot + 255) / 256, 256, 0, stream>>>(w2, w2T, 1536, 384, 24, 24, 0, tot);
  tot = 384 * 128;
  tcvt_frag<<<(tot + 255) / 256, 256, 0, stream>>>(head_w, hdT, 384, 95, 8, 8, 0, tot);

  embed_kernel<<<(Mn * 96) / 256, 256, 0, stream>>>(idx, tok_emb, pos_emb, x);
  ln_kernel<<<Mn / 4, 256, 0, stream>>>(x, ln1_s, ln1_b, h);   // layer-0 LN1

  for (int l = 0; l < 6; l++) {
    gemm_h<4, false, 6, 72><<<2304, 256, 0, stream>>>(h, qkvT + l * 442368, nullptr, nullptr, qb);
    attn_kernel<<<Bn * Hn * 4, 256, 0, stream>>>(qb, kb, vb, ab);
    // WO + residual + LN2 fused -> x, h
    gemm_ln<6><<<256, 512, 0, stream>>>(ab, woT + l * 147456, bo + l * Dn, x, x,
                                        ln2_s + l * Dn, ln2_b + l * Dn, h);
    gemm_h<0, true, 6, 96><<<3072, 256, 0, stream>>>(h, w1T + l * 589824, b1 + l * FFn, nullptr, f1);
    // FFN2 + residual + LN1(next layer) / LNF fused -> x, h
    const float* ns = (l < 5) ? (ln1_s + (l + 1) * Dn) : lnf_s;
    const float* nb = (l < 5) ? (ln1_b + (l + 1) * Dn) : lnf_b;
    gemm_ln<24><<<256, 512, 0, stream>>>(f1, w2T + l * 589824, b2 + l * Dn, x, x,
                                         ns, nb, h);
  }
  gemm_h<3, false, 6, 8><<<256, 256, 0, stream>>>(h, hdT, head_b, nullptr, out);
}

// Round 7
// 1457.602 us; speedup vs baseline: 1.1275x; 1.1275x over previous
//
#include <hip/hip_runtime.h>
#include <hip/hip_bf16.h>
#include <cstdint>

#define DEV __device__ __forceinline__

typedef __hip_bfloat16 bf16;
typedef unsigned short u16;
typedef unsigned int u32;
typedef __attribute__((ext_vector_type(8))) short s8v;   // 8 bf16 (4 VGPRs) MFMA A/B frag
typedef __attribute__((ext_vector_type(4))) float f4;    // MFMA C/D frag

static constexpr int Bn = 128;
static constexpr int Tn = 256;
static constexpr int Dn = 384;
static constexpr int Hn = 6;
static constexpr int HDn = 64;
static constexpr int FFn = 1536;
static constexpr int Vn = 95;
static constexpr int Mn = Bn * 256;   // 32768

DEV u16 f2b(float f) {
  bf16 h = __float2bfloat16(f);
  return *reinterpret_cast<u16*>(&h);
}
DEV u32 pk2(float a, float b) { return (u32)f2b(a) | ((u32)f2b(b) << 16); }

// async 16B global->LDS. LDS destination is wave-uniform base + lane*16.
DEV void gl_lds16(const void* g, void* l) {
  auto gp = (const __attribute__((address_space(1))) u32*)(uintptr_t)g;
  auto lp = (__attribute__((address_space(3))) u32*)(u32)(uintptr_t)l;
  __builtin_amdgcn_global_load_lds(gp, lp, 16, 0, 0);
}

// counted vmcnt with literal immediate (folds under full unroll)
DEV void waitvm(int n) {
  if (n == 0)       asm volatile("s_waitcnt vmcnt(0)" ::: "memory");
  else if (n == 2)  asm volatile("s_waitcnt vmcnt(2)" ::: "memory");
  else if (n == 4)  asm volatile("s_waitcnt vmcnt(4)" ::: "memory");
  else if (n == 6)  asm volatile("s_waitcnt vmcnt(6)" ::: "memory");
  else if (n == 8)  asm volatile("s_waitcnt vmcnt(8)" ::: "memory");
  else if (n == 12) asm volatile("s_waitcnt vmcnt(12)" ::: "memory");
  else              asm volatile("s_waitcnt vmcnt(16)" ::: "memory");
}

// ---------------------------------------------------------------------------
// Hybrid GEMM — R4 single-barrier pipelined schedule (QKV / head).
// R0-R6 verdict: every dispatch runs at bytes / ~2.8 TB/s (mixed rw HBM
// ceiling); K-loop structure is NOT the binder. This kernel kept from the
// best-total round (R4).
// MODE 0: bf16 out [M,N]   MODE 3: f32 head out [M,95] col-guarded
// MODE 4: fused QKV: n<384 q; n<768 k; n>=768 v in vT layout [(b,h)][d][t]
// ---------------------------------------------------------------------------
template <int MODE, bool RELU, int NKT, int NT>
__global__ __launch_bounds__(256, 2) void gemm_h(
    const u16* __restrict__ A, const u16* __restrict__ Bw,
    const float* __restrict__ bias, const float* __restrict__ resid,
    void* __restrict__ outp)
{
  constexpr int K = NKT * 64;
  constexpr int N = NT * 16;
  constexpr int nTiles = NT / 8;
  __shared__ __align__(16) u16 As[3][128 * 64];
  const int tid = threadIdx.x;
  const int lane = tid & 63, wave = tid >> 6;
  const int quad = lane >> 4, l16 = lane & 15;
  const int wy = wave >> 1, wx = wave & 1;
  const int blk = blockIdx.x;
  const int xcd = blk & 7, tt = blk >> 3;
  const int nT = tt % nTiles, mT = xcd + 8 * (tt / nTiles);
  const int mBase = mT * 128, nBase = nT * 128;

  f4 acc[4][4] = {};

  int rS[4], cS[4];
#pragma unroll
  for (int i = 0; i < 4; i++) {
    int s = i * 256 + tid;
    rS[i] = s >> 3;
    cS[i] = ((s & 7) ^ (rS[i] & 7)) * 8;
  }

  const u16* Ab = A + (size_t)mBase * K;
  const u16* Bp = Bw + (size_t)((nBase >> 4) + wx * 4) * 512 + lane * 8;

#define STAGEA(buf, kt)                                                       \
  do {                                                                        \
    _Pragma("unroll")                                                         \
    for (int i = 0; i < 4; i++)                                               \
      gl_lds16(Ab + (size_t)rS[i] * K + (kt) + cS[i],                         \
               &As[buf][(i * 256 + wave * 64) * 8]);                          \
  } while (0)

  // prologue: issue order MUST be stage(0), bqa(0), stage(1)
  s8v bqa[2][4];
  STAGEA(0, 0);
  __builtin_amdgcn_sched_barrier(0);
#pragma unroll
  for (int j = 0; j < 4; j++)
    bqa[0][j] = *(const s8v*)(Bp + (size_t)0 * (NT * 512) + j * 512);
  __builtin_amdgcn_sched_barrier(0);
  STAGEA(1, 64);
  __builtin_amdgcn_sched_barrier(0);

  const int nk = NKT;
#pragma unroll
  for (int ik = 0; ik < nk; ik++) {
    const int cur = ik % 3;
    const int par = ik & 1;
    waitvm((ik + 1 < nk) ? 4 : 0);
    asm volatile("s_barrier" ::: "memory");
    s8v bqb[4];
#pragma unroll
    for (int j = 0; j < 4; j++)
      bqb[j] = *(const s8v*)(Bp + (size_t)(ik * 2 + 1) * (NT * 512) + j * 512);
    __builtin_amdgcn_sched_barrier(0);
    if (ik + 1 < nk) {
#pragma unroll
      for (int j = 0; j < 4; j++)
        bqa[par ^ 1][j] = *(const s8v*)(Bp + (size_t)(ik * 2 + 2) * (NT * 512) + j * 512);
    }
    __builtin_amdgcn_sched_barrier(0);
    if (ik + 2 < nk) STAGEA((ik + 2) % 3, (ik + 2) * 64);
    __builtin_amdgcn_sched_barrier(0);
    {
      s8v af[4];
#pragma unroll
      for (int i = 0; i < 4; i++) {
        int row = wy * 64 + i * 16 + l16;
        int ch = quad ^ (row & 7);
        af[i] = *(const s8v*)&As[cur][row * 64 + ch * 8];
      }
#pragma unroll
      for (int i = 0; i < 4; i++)
#pragma unroll
        for (int j = 0; j < 4; j++)
          acc[i][j] = __builtin_amdgcn_mfma_f32_16x16x32_bf16(af[i], bqa[par][j], acc[i][j], 0, 0, 0);
    }
    waitvm(4 * ((ik + 1 < nk) + (ik + 2 < nk)));
    {
      s8v af[4];
#pragma unroll
      for (int i = 0; i < 4; i++) {
        int row = wy * 64 + i * 16 + l16;
        int ch = (4 + quad) ^ (row & 7);
        af[i] = *(const s8v*)&As[cur][row * 64 + ch * 8];
      }
#pragma unroll
      for (int i = 0; i < 4; i++)
#pragma unroll
        for (int j = 0; j < 4; j++)
          acc[i][j] = __builtin_amdgcn_mfma_f32_16x16x32_bf16(af[i], bqb[j], acc[i][j], 0, 0, 0);
    }
  }
#undef STAGEA

  if (MODE == 0) {
    u16* out = (u16*)outp;
#pragma unroll
    for (int j = 0; j < 4; j++) {
      int n = nBase + wx * 64 + j * 16 + l16;
      float bv = bias ? bias[n] : 0.f;
#pragma unroll
      for (int i = 0; i < 4; i++) {
        int m0 = mBase + wy * 64 + i * 16 + quad * 4;
#pragma unroll
        for (int r = 0; r < 4; r++) {
          float v = acc[i][j][r] + bv;
          if (RELU) v = fmaxf(v, 0.f);
          out[(size_t)(m0 + r) * N + n] = f2b(v);
        }
      }
    }
  } else if (MODE == 3) {
    float* out = (float*)outp;
#pragma unroll
    for (int j = 0; j < 4; j++) {
      int n = nBase + wx * 64 + j * 16 + l16;
      if (n < Vn) {
        float bv = bias[n];
#pragma unroll
        for (int i = 0; i < 4; i++) {
          int m0 = mBase + wy * 64 + i * 16 + quad * 4;
#pragma unroll
          for (int r = 0; r < 4; r++)
            out[(size_t)(m0 + r) * Vn + n] = acc[i][j][r] + bv;
        }
      }
    }
  } else if (MODE == 4) {
    u16* qb = (u16*)outp;
    u16* kb = qb + (size_t)Mn * 384;
    u16* vb = kb + (size_t)Mn * 384;
#pragma unroll
    for (int j = 0; j < 4; j++) {
      int n = nBase + wx * 64 + j * 16 + l16;
      if (n < 768) {
        u16* dst = (n < 384) ? qb : kb;
        int col = (n < 384) ? n : (n - 384);   // 384 is NOT pow2 — no mask!
#pragma unroll
        for (int i = 0; i < 4; i++) {
          int m0 = mBase + wy * 64 + i * 16 + quad * 4;
#pragma unroll
          for (int r = 0; r < 4; r++)
            dst[(size_t)(m0 + r) * 384 + col] = f2b(acc[i][j][r]);
        }
      } else {
        int n7 = n - 768;
        int hh = n7 >> 6, d = n7 & 63;
#pragma unroll
        for (int i = 0; i < 4; i++) {
          int m0 = mBase + wy * 64 + i * 16 + quad * 4;
          int b = m0 >> 8, t0 = m0 & 255;
          uint2 w;
          w.x = pk2(acc[i][j][0], acc[i][j][1]);
          w.y = pk2(acc[i][j][2], acc[i][j][3]);
          *(uint2*)&vb[((b * Hn + hh) * HDn + d) * Tn + t0] = w;
        }
      }
    }
  }
}

// ---------------------------------------------------------------------------
// WO GEMM + residual-add + LayerNorm fusion (N=384 full-row tile), R6 form.
// ---------------------------------------------------------------------------
template <int NKT>
__global__ __launch_bounds__(512, 2) void gemm_ln(
    const u16* __restrict__ A, const u16* __restrict__ Bw,
    const float* __restrict__ bias, const float* __restrict__ resid,
    float* __restrict__ xout,
    const float* __restrict__ sc, const float* __restrict__ bi,
    u16* __restrict__ hout)
{
  constexpr int K = NKT * 64;
  constexpr int NT = 24;               // 384 / 16
  __shared__ __align__(16) u16 As[2][128 * 64];
  __shared__ __align__(16) u16 Bs[2][24576];      // 2 ks x 24 nt x 512
  __shared__ float2 red[4][128];
  const int tid = threadIdx.x;
  const int lane = tid & 63, wave = tid >> 6;       // 0..7
  const int quad = lane >> 4, l16 = lane & 15;
  const int wy = wave >> 2, wx = wave & 3;          // 2 x 4
  const int blk = blockIdx.x;
  const int mT = (blk & 7) + 8 * (blk >> 3);        // XCD-major
  const int mBase = mT * 128;

  f4 acc[4][6] = {};

  int rS[2], cS[2];
#pragma unroll
  for (int i = 0; i < 2; i++) {
    int s = i * 512 + tid;
    rS[i] = s >> 3;
    cS[i] = ((s & 7) ^ (rS[i] & 7)) * 8;
  }

  const u16* Ab = A + (size_t)mBase * K;

#define STAGEL(buf, kt)                                                       \
  do {                                                                        \
    _Pragma("unroll")                                                         \
    for (int i = 0; i < 2; i++)                                               \
      gl_lds16(Ab + (size_t)rS[i] * K + (kt) + cS[i],                         \
               &As[buf][(i * 512 + wave * 64) * 8]);                          \
  } while (0)

#define STAGEB2(buf, ikk)                                                     \
  do {                                                                        \
    _Pragma("unroll")                                                         \
    for (int L = 0; L < 6; L++) {                                             \
      int ks = L / 3, th = L % 3;                                             \
      int c = th * 4096 + tid * 8;                                            \
      gl_lds16(Bw + (size_t)((ikk) * 2 + ks) * (NT * 512) + c,                \
               &Bs[buf][ks * 12288 + c]);                                     \
    }                                                                         \
  } while (0)

  STAGEL(0, 0);
  STAGEB2(0, 0);

  const int nk = NKT;
#pragma unroll
  for (int ik = 0; ik < nk; ik++) {
    const int cur = ik & 1;
    asm volatile("s_waitcnt vmcnt(0)" ::: "memory");
    asm volatile("s_barrier" ::: "memory");
    if (ik + 1 < nk) {
      STAGEL(cur ^ 1, (ik + 1) * 64);
      STAGEB2(cur ^ 1, ik + 1);
    }
    __builtin_amdgcn_sched_barrier(0);
#pragma unroll
    for (int ks = 0; ks < 2; ks++) {
      s8v af[4], bq[6];
#pragma unroll
      for (int i = 0; i < 4; i++) {
        int row = wy * 64 + i * 16 + l16;
        int ch = (ks * 4 + quad) ^ (row & 7);
        af[i] = *(const s8v*)&As[cur][row * 64 + ch * 8];
      }
#pragma unroll
      for (int j = 0; j < 6; j++)
        bq[j] = *(const s8v*)&Bs[cur][ks * 12288 + (wx * 6 + j) * 512 + lane * 8];
#pragma unroll
      for (int i = 0; i < 4; i++)
#pragma unroll
        for (int j = 0; j < 6; j++)
          acc[i][j] = __builtin_amdgcn_mfma_f32_16x16x32_bf16(af[i], bq[j], acc[i][j], 0, 0, 0);
    }
  }
#undef STAGEL
#undef STAGEB2

  // ---- epilogue: x = resid + C + bias; row stats; h = LN(x)*sc + bi ----
  f4 psum[4] = {}, psq[4] = {};
#pragma unroll
  for (int j = 0; j < 6; j++) {
    int n = wx * 96 + j * 16 + l16;
    float bv = bias[n];
#pragma unroll
    for (int i = 0; i < 4; i++) {
      int m0 = mBase + wy * 64 + i * 16 + quad * 4;
#pragma unroll
      for (int r = 0; r < 4; r++) {
        int m = m0 + r;
        float v = resid[(size_t)m * Dn + n] + acc[i][j][r] + bv;
        xout[(size_t)m * Dn + n] = v;
        acc[i][j][r] = v;
        psum[i][r] += v;
        psq[i][r] += v * v;
      }
    }
  }
#pragma unroll
  for (int o = 1; o < 16; o <<= 1)
#pragma unroll
    for (int i = 0; i < 4; i++)
#pragma unroll
      for (int r = 0; r < 4; r++) {
        psum[i][r] += __shfl_xor(psum[i][r], o);
        psq[i][r] += __shfl_xor(psq[i][r], o);
      }
  if (l16 == 0) {
#pragma unroll
    for (int i = 0; i < 4; i++)
#pragma unroll
      for (int r = 0; r < 4; r++) {
        int lr = wy * 64 + i * 16 + quad * 4 + r;
        float2 p; p.x = psum[i][r]; p.y = psq[i][r];
        red[wx][lr] = p;
      }
  }
  __syncthreads();
  float scv[6], biv[6];
#pragma unroll
  for (int j = 0; j < 6; j++) {
    int n = wx * 96 + j * 16 + l16;
    scv[j] = sc[n];
    biv[j] = bi[n];
  }
#pragma unroll
  for (int i = 0; i < 4; i++)
#pragma unroll
    for (int r = 0; r < 4; r++) {
      int lr = wy * 64 + i * 16 + quad * 4 + r;
      float ts = 0.f, tq = 0.f;
#pragma unroll
      for (int w = 0; w < 4; w++) { float2 p = red[w][lr]; ts += p.x; tq += p.y; }
      float mean = ts * (1.f / 384.f);
      float inv = rsqrtf(tq * (1.f / 384.f) - mean * mean + 1e-5f);
      int m = mBase + lr;
#pragma unroll
      for (int j = 0; j < 6; j++) {
        int n = wx * 96 + j * 16 + l16;
        hout[(size_t)m * Dn + n] = f2b((acc[i][j][r] - mean) * inv * scv[j] + biv[j]);
      }
    }
}

// ---------------------------------------------------------------------------
// R7: FUSED FFN — h@W1 + b1 -> relu -> @W2 + b2 + resid -> x, LN(x) -> h'.
// Eliminates the f1 intermediate entirely (~200 MB HBM/layer at the measured
// ~2.8 TB/s mixed-rw ceiling = the single biggest traffic item).
//
// Block = 128 rows, 8 waves (wy=wave>>2 in {0,1}, wx=wave&3), 1 block/CU,
// grid 256 = one block per CU exactly.
//  - Hs[128][384] staged ONCE (96 KB, chunk-XOR swizzle; pre-swizzled global
//    source, linear LDS dest per gl_lds16 rules).
//  - 12 ff-chunks of 128:
//      GEMM1 (K=384): acc1 = mfma(W1frag, hfrag) SWAPPED -> thread holds
//        P(m = ..+l16, ff = ..+quad*4+r): 4 consecutive ff -> bias+relu+pk2
//        -> uint2 write to Ps (32 KB, byte^((m&7)<<4) swizzle).
//      barrier; GEMM2 (K=128): acc2 += mfma(P-frag, W2frag); barrier.
//    bq2 ks2=0 prefetched BEFORE the P-write barrier (global, Ps-independent).
//  - Epilogue: x = resid + acc2 + b2; row-LN -> h' (same as gemm_ln).
// LDS 96+32+4 = 132 KB. VGPR ~ acc2 96 + acc1 32 + bq2 dbuf 48 + transient.
// ---------------------------------------------------------------------------
__global__ __launch_bounds__(512, 2) void ffn_ln(
    const u16* __restrict__ A, const u16* __restrict__ B1w,
    const float* __restrict__ b1, const u16* __restrict__ B2w,
    const float* __restrict__ b2, const float* __restrict__ resid,
    float* __restrict__ xout,
    const float* __restrict__ sc, const float* __restrict__ bi,
    u16* __restrict__ hout)
{
  __shared__ __align__(16) u16 Hs[128 * 384];   // 96 KB
  __shared__ __align__(16) u16 Ps[128 * 128];   // 32 KB
  __shared__ float2 red[4][128];
  const int tid = threadIdx.x;
  const int lane = tid & 63, wave = tid >> 6;
  const int quad = lane >> 4, l16 = lane & 15;
  const int wy = wave >> 2, wx = wave & 3;
  const int mT = (blockIdx.x & 7) + 8 * (blockIdx.x >> 3);
  const int mBase = mT * 128;
  char* Psb = (char*)Ps;

  // ---- stage Hs once: slot S=i*512+tid (wave-uniform+lane), row=S/48 ----
  {
    const u16* hg = A + (size_t)mBase * Dn;
#pragma unroll
    for (int i = 0; i < 12; i++) {
      u32 S = i * 512 + tid;
      u32 row = S / 48u;
      u32 c = S - row * 48u;
      u32 srcc = (c & ~7u) | ((c & 7u) ^ (row & 7u));
      gl_lds16(hg + (size_t)row * Dn + srcc * 8, &Hs[S * 8]);
    }
  }
  asm volatile("s_waitcnt vmcnt(0)" ::: "memory");
  asm volatile("s_barrier" ::: "memory");

  f4 acc2[4][6] = {};
  const u16* B1p = B1w + (size_t)(wx * 2) * 512 + lane * 8;
  const u16* B2p = B2w + (size_t)(wx * 6) * 512 + lane * 8;
  s8v bq2[2][6];

#pragma unroll 1
  for (int c = 0; c < 12; c++) {
    // ---------------- GEMM1: P = relu(h @ W1[:,c*128..] + b1) -------------
    float4 b1v0 = *(const float4*)&b1[c * 128 + wx * 32 + quad * 4];
    float4 b1v1 = *(const float4*)&b1[c * 128 + wx * 32 + 16 + quad * 4];
    __builtin_amdgcn_sched_barrier(0);
    s8v bq1[2][4];
#pragma unroll
    for (int u = 0; u < 4; u++) {
      int ks = u >> 1, j = u & 1;
      bq1[0][u] = *(const s8v*)(B1p + (size_t)(ks * 96 + c * 8 + j) * 512);
    }
    __builtin_amdgcn_sched_barrier(0);
    f4 acc1[4][2] = {};
#pragma unroll
    for (int ik = 0; ik < 6; ik++) {
      const int par = ik & 1;
      if (ik + 1 < 6) {
#pragma unroll
        for (int u = 0; u < 4; u++) {
          int ks = u >> 1, j = u & 1;
          bq1[par ^ 1][u] = *(const s8v*)(B1p + (size_t)(((ik + 1) * 2 + ks) * 96 + c * 8 + j) * 512);
        }
      }
      __builtin_amdgcn_sched_barrier(0);
      waitvm((ik + 1 < 6) ? 4 : 0);   // retire bq1[par] (+b1 at ik=0)
#pragma unroll
      for (int ks = 0; ks < 2; ks++) {
        s8v af[4];
#pragma unroll
        for (int i = 0; i < 4; i++) {
          int row = wy * 64 + i * 16 + l16;
          int ch = ik * 8 + ((ks * 4 + quad) ^ (row & 7));
          af[i] = *(const s8v*)&Hs[row * 384 + ch * 8];
        }
#pragma unroll
        for (int i = 0; i < 4; i++)
#pragma unroll
          for (int j = 0; j < 2; j++)
            acc1[i][j] = __builtin_amdgcn_mfma_f32_16x16x32_bf16(
                bq1[par][ks * 2 + j], af[i], acc1[i][j], 0, 0, 0);
      }
    }
    // prefetch bq2 ks2=0 (independent of Ps) before the barrier
#pragma unroll
    for (int j = 0; j < 6; j++)
      bq2[0][j] = *(const s8v*)(B2p + (size_t)((c * 4) * 24 + j) * 512);
    __builtin_amdgcn_sched_barrier(0);
    // ---- P write: bias + relu + pack; swizzled uint2 stores ----
#pragma unroll
    for (int i = 0; i < 4; i++) {
      int m = wy * 64 + i * 16 + l16;
#pragma unroll
      for (int j = 0; j < 2; j++) {
        float4 bv4 = (j == 0) ? b1v0 : b1v1;
        float v0 = fmaxf(acc1[i][j][0] + bv4.x, 0.f);
        float v1 = fmaxf(acc1[i][j][1] + bv4.y, 0.f);
        float v2 = fmaxf(acc1[i][j][2] + bv4.z, 0.f);
        float v3 = fmaxf(acc1[i][j][3] + bv4.w, 0.f);
        uint2 w; w.x = pk2(v0, v1); w.y = pk2(v2, v3);
        int byteoff = (m * 256 + (wx * 32 + j * 16 + quad * 4) * 2) ^ ((m & 7) << 4);
        *(uint2*)(Psb + byteoff) = w;
      }
    }
    asm volatile("s_waitcnt lgkmcnt(0)" ::: "memory");
    asm volatile("s_barrier" ::: "memory");
    // ---------------- GEMM2: acc2 += P @ W2[c*128.., :] -------------------
#pragma unroll
    for (int ks2 = 0; ks2 < 4; ks2++) {
      const int p2 = ks2 & 1;
      if (ks2 + 1 < 4) {
#pragma unroll
        for (int j = 0; j < 6; j++)
          bq2[p2 ^ 1][j] = *(const s8v*)(B2p + (size_t)((c * 4 + ks2 + 1) * 24 + j) * 512);
      }
      __builtin_amdgcn_sched_barrier(0);
      waitvm((ks2 + 1 < 4) ? 6 : 0);
      s8v af2[4];
#pragma unroll
      for (int i = 0; i < 4; i++) {
        int m = wy * 64 + i * 16 + l16;
        int byteoff = (m * 256 + (ks2 * 4 + quad) * 16) ^ ((m & 7) << 4);
        af2[i] = *(const s8v*)(Psb + byteoff);
      }
#pragma unroll
      for (int i = 0; i < 4; i++)
#pragma unroll
        for (int j = 0; j < 6; j++)
          acc2[i][j] = __builtin_amdgcn_mfma_f32_16x16x32_bf16(
              af2[i], bq2[p2][j], acc2[i][j], 0, 0, 0);
    }
    asm volatile("s_waitcnt lgkmcnt(0)" ::: "memory");
    asm volatile("s_barrier" ::: "memory");   // WAR: Ps free for next chunk
  }

  // ---- epilogue: x = resid + acc2 + b2; row stats; h' = LN(x)*sc+bi ----
  f4 psum[4] = {}, psq[4] = {};
#pragma unroll
  for (int j = 0; j < 6; j++) {
    int n = wx * 96 + j * 16 + l16;
    float bv = b2[n];
#pragma unroll
    for (int i = 0; i < 4; i++) {
      int m0 = mBase + wy * 64 + i * 16 + quad * 4;
#pragma unroll
      for (int r = 0; r < 4; r++) {
        int m = m0 + r;
        float v = resid[(size_t)m * Dn + n] + acc2[i][j][r] + bv;
        xout[(size_t)m * Dn + n] = v;
        acc2[i][j][r] = v;
        psum[i][r] += v;
        psq[i][r] += v * v;
      }
    }
  }
#pragma unroll
  for (int o = 1; o < 16; o <<= 1)
#pragma unroll
    for (int i = 0; i < 4; i++)
#pragma unroll
      for (int r = 0; r < 4; r++) {
        psum[i][r] += __shfl_xor(psum[i][r], o);
        psq[i][r] += __shfl_xor(psq[i][r], o);
      }
  if (l16 == 0) {
#pragma unroll
    for (int i = 0; i < 4; i++)
#pragma unroll
      for (int r = 0; r < 4; r++) {
        int lr = wy * 64 + i * 16 + quad * 4 + r;
        float2 p; p.x = psum[i][r]; p.y = psq[i][r];
        red[wx][lr] = p;
      }
  }
  __syncthreads();
  float scv[6], biv[6];
#pragma unroll
  for (int j = 0; j < 6; j++) {
    int n = wx * 96 + j * 16 + l16;
    scv[j] = sc[n];
    biv[j] = bi[n];
  }
#pragma unroll
  for (int i = 0; i < 4; i++)
#pragma unroll
    for (int r = 0; r < 4; r++) {
      int lr = wy * 64 + i * 16 + quad * 4 + r;
      float ts = 0.f, tq = 0.f;
#pragma unroll
      for (int w = 0; w < 4; w++) { float2 p = red[w][lr]; ts += p.x; tq += p.y; }
      float mean = ts * (1.f / 384.f);
      float inv = rsqrtf(tq * (1.f / 384.f) - mean * mean + 1e-5f);
      int m = mBase + lr;
#pragma unroll
      for (int j = 0; j < 6; j++) {
        int n = wx * 96 + j * 16 + l16;
        hout[(size_t)m * Dn + n] = f2b((acc2[i][j][r] - mean) * inv * scv[j] + biv[j]);
      }
    }
}

// ---------------------------------------------------------------------------
// Flash-chunked attention v2 (unchanged).
// ---------------------------------------------------------------------------
__global__ __launch_bounds__(256) void attn_kernel(
    const u16* __restrict__ q, const u16* __restrict__ k,
    const u16* __restrict__ vT, u16* __restrict__ ao)
{
  __shared__ __align__(16) u16 Psh[4][2][16 * 40];
  const int tid = threadIdx.x, lane = tid & 63, wave = tid >> 6;
  const int quad = lane >> 4, l16 = lane & 15;
  const int c4 = blockIdx.x / 768;
  const int bh = blockIdx.x - c4 * 768;
  const int b = bh / Hn, h = bh % Hn;
  const u16* qg = q + (b * Tn) * Dn + h * HDn;
  const u16* kg = k + (b * Tn) * Dn + h * HDn;
  const u16* vg = vT + bh * (HDn * Tn);
  u16* aog = ao + (b * Tn) * Dn + h * HDn;
  const float c1 = 0.125f * 1.44269504f;  // scale * log2(e)

  const int qt = (wave & 2) ? ((wave & 1) ? 15 - c4 : 8 + c4)
                            : ((wave & 1) ? 7 - c4 : c4);
  const int qglob = qt * 16 + l16;

  const s8v qf0 = *(const s8v*)&qg[qglob * Dn + quad * 8];
  const s8v qf1 = *(const s8v*)&qg[qglob * Dn + 32 + quad * 8];

  float lsum = 0.f;
  f4 O[4] = {};

  const int nch = qt / 2 + 1;
  for (int c2 = 0; c2 < nch; c2++) {
    const int kk0 = c2 * 32;
    f4 S0 = {0.f, 0.f, 0.f, 0.f}, S1 = S0;
    {
      s8v kf = *(const s8v*)&kg[(kk0 + l16) * Dn + quad * 8];
      S0 = __builtin_amdgcn_mfma_f32_16x16x32_bf16(kf, qf0, S0, 0, 0, 0);
      kf = *(const s8v*)&kg[(kk0 + l16) * Dn + 32 + quad * 8];
      S0 = __builtin_amdgcn_mfma_f32_16x16x32_bf16(kf, qf1, S0, 0, 0, 0);
    }
    if (kk0 + 16 <= qt * 16) {
      s8v kf = *(const s8v*)&kg[(kk0 + 16 + l16) * Dn + quad * 8];
      S1 = __builtin_amdgcn_mfma_f32_16x16x32_bf16(kf, qf0, S1, 0, 0, 0);
      kf = *(const s8v*)&kg[(kk0 + 16 + l16) * Dn + 32 + quad * 8];
      S1 = __builtin_amdgcn_mfma_f32_16x16x32_bf16(kf, qf1, S1, 0, 0, 0);
    }
    const int kkq = kk0 + quad * 4;
    f4 E0, E1;
#pragma unroll
    for (int r = 0; r < 4; r++) {
      E0[r] = (kkq + r <= qglob) ? exp2f(S0[r] * c1) : 0.f;
      E1[r] = (kkq + 16 + r <= qglob) ? exp2f(S1[r] * c1) : 0.f;
      lsum += E0[r] + E1[r];
    }
    u16* prow = &Psh[wave][c2 & 1][l16 * 40];
    uint2 w0, w1;
    w0.x = pk2(E0[0], E0[1]); w0.y = pk2(E0[2], E0[3]);
    w1.x = pk2(E1[0], E1[1]); w1.y = pk2(E1[2], E1[3]);
    *(uint2*)&prow[quad * 4] = w0;
    *(uint2*)&prow[16 + quad * 4] = w1;
    const s8v pf = *(const s8v*)&prow[quad * 8];
#pragma unroll
    for (int dm = 0; dm < 4; dm++) {
      s8v vf = *(const s8v*)&vg[(dm * 16 + l16) * Tn + kk0 + quad * 8];
      O[dm] = __builtin_amdgcn_mfma_f32_16x16x32_bf16(vf, pf, O[dm], 0, 0, 0);
    }
  }

  lsum += __shfl_xor(lsum, 16);
  lsum += __shfl_xor(lsum, 32);
  const float inv = 1.0f / lsum;
#pragma unroll
  for (int dm = 0; dm < 4; dm++) {
    uint2 w;
    w.x = pk2(O[dm][0] * inv, O[dm][1] * inv);
    w.y = pk2(O[dm][2] * inv, O[dm][3] * inv);
    *(uint2*)&aog[qglob * Dn + dm * 16 + quad * 4] = w;
  }
}

// ---------------------------------------------------------------------------
// LayerNorm: one wave per token — used ONCE (after embed, layer-0 LN1).
// ---------------------------------------------------------------------------
__global__ __launch_bounds__(256) void ln_kernel(
    const float* __restrict__ x, const float* __restrict__ sc,
    const float* __restrict__ bi, u16* __restrict__ out)
{
  int tok = blockIdx.x * 4 + (threadIdx.x >> 6);
  int lane = threadIdx.x & 63;
  const float* xr = x + (size_t)tok * Dn;
  float v[6];
  float s = 0.f, sq = 0.f;
#pragma unroll
  for (int i = 0; i < 6; i++) {
    v[i] = xr[lane + 64 * i];
    s += v[i];
    sq += v[i] * v[i];
  }
#pragma unroll
  for (int o = 1; o < 64; o <<= 1) {
    s += __shfl_xor(s, o);
    sq += __shfl_xor(sq, o);
  }
  float mean = s * (1.f / 384.f);
  float var = sq * (1.f / 384.f) - mean * mean;
  float inv = rsqrtf(var + 1e-5f);
  u16* orow = out + (size_t)tok * Dn;
#pragma unroll
  for (int i = 0; i < 6; i++) {
    int c = lane + 64 * i;
    orow[c] = f2b((v[i] - mean) * inv * sc[c] + bi[c]);
  }
}

// x[m][:] = tok_emb[idx[m]][:] + pos_emb[m%T][:]  (float4 per thread)
__global__ __launch_bounds__(256) void embed_kernel(
    const int* __restrict__ idx, const float* __restrict__ tok,
    const float* __restrict__ pos, float* __restrict__ x)
{
  int i = blockIdx.x * 256 + threadIdx.x;  // [0, M*96)
  int m = i / 96, c = (i - m * 96) * 4;
  int t = m & (Tn - 1);
  const float4 tv = *(const float4*)&tok[idx[m] * Dn + c];
  const float4 pv = *(const float4*)&pos[t * Dn + c];
  float4 r;
  r.x = tv.x + pv.x; r.y = tv.y + pv.y; r.z = tv.z + pv.z; r.w = tv.w + pv.w;
  *(float4*)&x[m * Dn + c] = r;
}

// ---------------------------------------------------------------------------
// Weight converter -> MFMA B-fragment order.
// dst[((l*KC + kc)*NTtot + ntoff + nt)*512 + lane*8 + j8] = w[l][k][n] (bf16)
//   where k = kc*32 + (lane>>4)*8 + j8, n = nt*16 + (lane&15), zero if n >= C.
// ---------------------------------------------------------------------------
__global__ __launch_bounds__(256) void tcvt_frag(
    const float* __restrict__ src, u16* __restrict__ dst,
    int K, int C, int NTsub, int NTtot, int ntoff, int total)
{
  int t = blockIdx.x * 256 + threadIdx.x;
  if (t >= total) return;
  int j8 = t & 7;
  int lane = (t >> 3) & 63;
  int rest = t >> 9;
  int nt = rest % NTsub;
  int lkc = rest / NTsub;
  int KC = K >> 5;
  int kc = lkc % KC;
  int l = lkc / KC;
  int quad = lane >> 4, l16 = lane & 15;
  int k = kc * 32 + quad * 8 + j8;
  int n = nt * 16 + l16;
  float v = (n < C) ? src[((size_t)l * K + k) * C + n] : 0.f;
  dst[((size_t)(l * KC + kc) * NTtot + ntoff + nt) * 512 + lane * 8 + j8] = f2b(v);
}

extern "C" void kernel_launch(void* const* d_in, const int* in_sizes, int n_in,
                              void* d_out, int out_size, void* d_ws, size_t ws_size,
                              hipStream_t stream)
{
  (void)in_sizes; (void)n_in; (void)out_size;
  const int*   idx     = (const int*)d_in[0];
  const float* tok_emb = (const float*)d_in[1];
  const float* pos_emb = (const float*)d_in[2];
  const float* ln1_s   = (const float*)d_in[3];
  const float* ln1_b   = (const float*)d_in[4];
  const float* wq      = (const float*)d_in[5];
  const float* wk      = (const float*)d_in[6];
  const float* wv      = (const float*)d_in[7];
  const float* wo      = (const float*)d_in[8];
  const float* bo      = (const float*)d_in[9];
  const float* ln2_s   = (const float*)d_in[10];
  const float* ln2_b   = (const float*)d_in[11];
  const float* w1      = (const float*)d_in[12];
  const float* b1      = (const float*)d_in[13];
  const float* w2      = (const float*)d_in[14];
  const float* b2      = (const float*)d_in[15];
  const float* lnf_s   = (const float*)d_in[16];
  const float* lnf_b   = (const float*)d_in[17];
  const float* head_w  = (const float*)d_in[18];
  const float* head_b  = (const float*)d_in[19];
  float* out = (float*)d_out;

  // workspace layout (bytes)
  char* ws = (char*)d_ws;
  float* x  = (float*)(ws + 0);             // 50,331,648  fp32 residual stream
  u16*   h  = (u16*)(ws + 50331648);        // 25,165,824  LN output (bf16)
  u16*   qb = (u16*)(ws + 75497472);        // 25,165,824  (q,k,v contiguous!)
  u16*   kb = (u16*)(ws + 100663296);       // 25,165,824
  u16*   vb = (u16*)(ws + 125829120);       // 25,165,824  V^T [(b,h)][d][t]
  u16*   ab = (u16*)(ws + 150994944);       // 25,165,824  attn out
  u16* qkvT = (u16*)(ws + 176160768);       // 6 * 442368 (frag layout, NTtot=72)
  u16* woT  = qkvT + 6 * 442368;            // 6 * 147456 (NTtot=24)
  u16* w1T  = woT + 6 * 147456;             // 6 * 589824 (NTtot=96, K=384)
  u16* w2T  = w1T + 6 * 589824;             // 6 * 589824 (NTtot=24, K=1536)
  u16* hdT  = w2T + 6 * 589824;             // 49152 (NTtot=8, 95->128 pad)
  if (ws_size < (size_t)197492736) return;

  int tot = 6 * 384 * 384;
  tcvt_frag<<<(tot + 255) / 256, 256, 0, stream>>>(wq, qkvT, 384, 384, 24, 72, 0, tot);
  tcvt_frag<<<(tot + 255) / 256, 256, 0, stream>>>(wk, qkvT, 384, 384, 24, 72, 24, tot);
  tcvt_frag<<<(tot + 255) / 256, 256, 0, stream>>>(wv, qkvT, 384, 384, 24, 72, 48, tot);
  tcvt_frag<<<(tot + 255) / 256, 256, 0, stream>>>(wo, woT, 384, 384, 24, 24, 0, tot);
  tot = 6 * 384 * 1536;
  tcvt_frag<<<(tot + 255) / 256, 256, 0, stream>>>(w1, w1T, 384, 1536, 96, 96, 0, tot);
  tcvt_frag<<<(tot + 255) / 256, 256, 0, stream>>>(w2, w2T, 1536, 384, 24, 24, 0, tot);
  tot = 384 * 128;
  tcvt_frag<<<(tot + 255) / 256, 256, 0, stream>>>(head_w, hdT, 384, 95, 8, 8, 0, tot);

  embed_kernel<<<(Mn * 96) / 256, 256, 0, stream>>>(idx, tok_emb, pos_emb, x);
  ln_kernel<<<Mn / 4, 256, 0, stream>>>(x, ln1_s, ln1_b, h);   // layer-0 LN1

  for (int l = 0; l < 6; l++) {
    gemm_h<4, false, 6, 72><<<2304, 256, 0, stream>>>(h, qkvT + l * 442368, nullptr, nullptr, qb);
    attn_kernel<<<Bn * Hn * 4, 256, 0, stream>>>(qb, kb, vb, ab);
    // WO + residual + LN2 fused -> x, h
    gemm_ln<6><<<256, 512, 0, stream>>>(ab, woT + l * 147456, bo + l * Dn, x, x,
                                        ln2_s + l * Dn, ln2_b + l * Dn, h);
    // FFN1+relu+FFN2 + residual + LN1(next)/LNF fused -> x, h  (f1 eliminated)
    const float* ns = (l < 5) ? (ln1_s + (l + 1) * Dn) : lnf_s;
    const float* nb = (l < 5) ? (ln1_b + (l + 1) * Dn) : lnf_b;
    ffn_ln<<<256, 512, 0, stream>>>(h, w1T + l * 589824, b1 + l * FFn,
                                    w2T + l * 589824, b2 + l * Dn,
                                    x, x, ns, nb, h);
  }
  gemm_h<3, false, 6, 8><<<256, 256, 0, stream>>>(h, hdT, head_b, nullptr, out);
}